// Round 1
// baseline (100.763 us; speedup 1.0000x reference)
//
#include <hip/hip_runtime.h>
#include <hip/hip_bf16.h>

// Quantizer (VQ-VAE): inputs [32,2048,256] f32, embed [1024,256] f32.
// out = (quantized [32,2048,256] f32, latent_loss scalar f32) concatenated.
//
// Pipeline:
//   prep_kernel   : embed -> bf16 copy (ws) + cneg[k] = -0.5*||e_k||^2 (exact fp32)
//   argmin_kernel : fused bf16-MFMA distance + argmin -> indices (ws)
//   gather_kernel : quantized = embed[idx] (fp32 exact) + block partial sums of (q-x)^2
//   loss_kernel   : deterministic final reduce -> 1.25 * mean((q-x)^2)

#define DIM     256
#define M_ROWS  65536
#define NCODES  1024

using bf16x8  = __attribute__((ext_vector_type(8))) short;
using f32x4   = __attribute__((ext_vector_type(4))) float;
using short4v = __attribute__((ext_vector_type(4))) short;

__device__ inline short f2bf(float f) {
  __hip_bfloat16 h = __float2bfloat16(f);   // RTNE
  union { __hip_bfloat16 h; short s; } u;
  u.h = h;
  return u.s;
}

// ---------------------------------------------------------------- prep
__global__ __launch_bounds__(64) void prep_kernel(const float* __restrict__ ew,
                                                  short* __restrict__ ebf,
                                                  float* __restrict__ cneg) {
  const int code = blockIdx.x;
  const int lane = threadIdx.x;
  float4 v = *((const float4*)(ew + (size_t)code * DIM) + lane);
  short4v o;
  o.x = f2bf(v.x); o.y = f2bf(v.y); o.z = f2bf(v.z); o.w = f2bf(v.w);
  *((short4v*)(ebf + (size_t)code * DIM) + lane) = o;
  float ss = v.x * v.x + v.y * v.y + v.z * v.z + v.w * v.w;
#pragma unroll
  for (int off = 32; off > 0; off >>= 1) ss += __shfl_xor(ss, off, 64);
  if (lane == 0) cneg[code] = -0.5f * ss;
}

// ---------------------------------------------------------------- argmin
// 128-row tile per block, loop 8 chunks of 128 codes. 4 waves in 2x2.
// Maximize s = x.e - 0.5*||e||^2  (== argmin distance).
// Key packing: s with low 10 mantissa bits replaced by (1023-code): argmin
// becomes a pure fmax chain; perturbation ~1024 ulp (~1e-6) << bf16 noise.
__global__ __launch_bounds__(256) void argmin_kernel(const float* __restrict__ x,
                                                     const short* __restrict__ ebf,
                                                     const float* __restrict__ cneg,
                                                     int* __restrict__ out_idx) {
  __shared__ short Xs[128 * 256];        // 64 KiB, bf16, XOR-swizzled
  __shared__ short Es[128 * 256];        // 64 KiB, bf16, XOR-swizzled
  __shared__ float cands[2][128];

  const int tid  = threadIdx.x;
  const int lane = tid & 63;
  const int wid  = tid >> 6;
  const int wr   = wid >> 1;             // wave row group (0..1)
  const int wc   = wid & 1;              // wave col group (0..1)
  const int l15  = lane & 15;
  const int lhi  = lane >> 4;            // 0..3
  const int row0 = blockIdx.x * 128;

  // ---- stage X tile: 128 rows x 256 cols fp32 -> bf16, swizzled ----
#pragma unroll
  for (int st = 0; st < 16; ++st) {
    int f8 = st * 256 + tid;             // 8-float unit, 0..4095
    int r  = f8 >> 5;                    // row 0..127 (32 units/row)
    int c8 = (f8 & 31) << 3;             // col start
    const float* src = x + (size_t)(row0 + r) * DIM + c8;
    float4 v0 = *(const float4*)src;
    float4 v1 = *(const float4*)(src + 4);
    union { bf16x8 v; short h[8]; } u;
    u.h[0] = f2bf(v0.x); u.h[1] = f2bf(v0.y); u.h[2] = f2bf(v0.z); u.h[3] = f2bf(v0.w);
    u.h[4] = f2bf(v1.x); u.h[5] = f2bf(v1.y); u.h[6] = f2bf(v1.z); u.h[7] = f2bf(v1.w);
    int di = (r * 256 + c8) ^ ((r & 7) << 3);
    *(bf16x8*)&Xs[di] = u.v;
  }

  f32x4 acc[4][4];
#pragma unroll
  for (int i = 0; i < 4; ++i)
#pragma unroll
    for (int j = 0; j < 4; ++j) acc[i][j] = f32x4{0.f, 0.f, 0.f, 0.f};

  float bk[4][4];                        // best packed keys per (mi, reg)
#pragma unroll
  for (int i = 0; i < 4; ++i)
#pragma unroll
    for (int r = 0; r < 4; ++r) bk[i][r] = -__builtin_inff();

  for (int chunk = 0; chunk < 8; ++chunk) {
    // ---- stage E chunk: 128 codes x 256 bf16, swizzled ----
#pragma unroll
    for (int st = 0; st < 16; ++st) {
      int f8 = st * 256 + tid;
      int r  = f8 >> 5;
      int c8 = (f8 & 31) << 3;
      bf16x8 v = *(const bf16x8*)(ebf + (size_t)(chunk * 128 + r) * DIM + c8);
      int di = (r * 256 + c8) ^ ((r & 7) << 3);
      *(bf16x8*)&Es[di] = v;
    }
    __syncthreads();

    float ct[4];
    unsigned tr[4];
#pragma unroll
    for (int nj = 0; nj < 4; ++nj) {
      int code = chunk * 128 + wc * 64 + nj * 16 + l15;
      ct[nj] = cneg[code];
      tr[nj] = (unsigned)(1023 - code);
    }

#pragma unroll
    for (int kk = 0; kk < 8; ++kk) {
      int colb = kk * 32 + lhi * 8;
      bf16x8 a[4], b[4];
#pragma unroll
      for (int mi = 0; mi < 4; ++mi) {
        int rr = wr * 64 + mi * 16 + l15;
        a[mi] = *(const bf16x8*)&Xs[(rr * 256 + colb) ^ ((rr & 7) << 3)];
      }
#pragma unroll
      for (int nj = 0; nj < 4; ++nj) {
        int cc = wc * 64 + nj * 16 + l15;
        b[nj] = *(const bf16x8*)&Es[(cc * 256 + colb) ^ ((cc & 7) << 3)];
      }
#pragma unroll
      for (int mi = 0; mi < 4; ++mi)
#pragma unroll
        for (int nj = 0; nj < 4; ++nj)
          acc[mi][nj] = __builtin_amdgcn_mfma_f32_16x16x32_bf16(a[mi], b[nj], acc[mi][nj], 0, 0, 0);
    }

    // ---- epilogue: fold chunk into running best keys, re-zero acc ----
#pragma unroll
    for (int mi = 0; mi < 4; ++mi) {
#pragma unroll
      for (int nj = 0; nj < 4; ++nj) {
        f32x4 v = acc[mi][nj];
#pragma unroll
        for (int r = 0; r < 4; ++r) {
          float sv = v[r] + ct[nj];
          unsigned kb = (__float_as_uint(sv) & 0xFFFFFC00u) | tr[nj];
          bk[mi][r] = fmaxf(bk[mi][r], __uint_as_float(kb));
        }
        acc[mi][nj] = f32x4{0.f, 0.f, 0.f, 0.f};
      }
    }
    __syncthreads();  // protect Es before next staging
  }

  // ---- reduce across the 16 code-lanes ----
#pragma unroll
  for (int mi = 0; mi < 4; ++mi)
#pragma unroll
    for (int r = 0; r < 4; ++r) {
      float v = bk[mi][r];
#pragma unroll
      for (int off = 1; off < 16; off <<= 1) v = fmaxf(v, __shfl_xor(v, off, 64));
      bk[mi][r] = v;
    }

  if (l15 == 0) {
#pragma unroll
    for (int mi = 0; mi < 4; ++mi)
#pragma unroll
      for (int r = 0; r < 4; ++r) {
        int row_local = wr * 64 + mi * 16 + lhi * 4 + r;
        cands[wc][row_local] = bk[mi][r];
      }
  }
  __syncthreads();
  if (tid < 128) {
    float k = fmaxf(cands[0][tid], cands[1][tid]);
    int code = 1023 - (int)(__float_as_uint(k) & 1023u);
    out_idx[row0 + tid] = code;
  }
}

// ---------------------------------------------------------------- gather + loss partials
__global__ __launch_bounds__(256) void gather_kernel(const float* __restrict__ x,
                                                     const float* __restrict__ ew,
                                                     const int* __restrict__ idx,
                                                     float* __restrict__ qout,
                                                     float* __restrict__ partials) {
  const int stride = 2048 * 256;
  float acc = 0.0f;
  int t = blockIdx.x * 256 + threadIdx.x;
#pragma unroll
  for (int it = 0; it < 8; ++it) {
    int i   = t + it * stride;           // float4 index, one row per wave
    int row = i >> 6;
    int d4  = (i & 63) << 2;
    int e   = idx[row];
    float4 q  = *(const float4*)(ew + (size_t)e * DIM + d4);
    float4 xv = *(const float4*)(x + ((size_t)i << 2));
    *(float4*)(qout + ((size_t)i << 2)) = q;
    float d0 = q.x - xv.x, d1 = q.y - xv.y, d2 = q.z - xv.z, d3 = q.w - xv.w;
    acc += d0 * d0 + d1 * d1 + d2 * d2 + d3 * d3;
  }
  __shared__ float red[256];
  red[threadIdx.x] = acc;
  __syncthreads();
  for (int s = 128; s > 0; s >>= 1) {
    if (threadIdx.x < s) red[threadIdx.x] += red[threadIdx.x + s];
    __syncthreads();
  }
  if (threadIdx.x == 0) partials[blockIdx.x] = red[0];
}

// ---------------------------------------------------------------- final loss
__global__ __launch_bounds__(256) void loss_kernel(const float* __restrict__ partials,
                                                   float* __restrict__ out_loss) {
  __shared__ double red[256];
  double a = 0.0;
  for (int i = threadIdx.x; i < 2048; i += 256) a += (double)partials[i];
  red[threadIdx.x] = a;
  __syncthreads();
  for (int s = 128; s > 0; s >>= 1) {
    if (threadIdx.x < s) red[threadIdx.x] += red[threadIdx.x + s];
    __syncthreads();
  }
  if (threadIdx.x == 0) out_loss[0] = (float)(1.25 * red[0] / 16777216.0);
}

// ---------------------------------------------------------------- launch
extern "C" void kernel_launch(void* const* d_in, const int* in_sizes, int n_in,
                              void* d_out, int out_size, void* d_ws, size_t ws_size,
                              hipStream_t stream) {
  const float* x  = (const float*)d_in[0];   // inputs [65536,256]
  const float* ew = (const float*)d_in[1];   // embed  [1024,256]
  float* out = (float*)d_out;

  char* ws = (char*)d_ws;
  short* ebf      = (short*)ws;                       // 512 KiB
  float* cneg     = (float*)(ws + 524288);            // 4 KiB
  int*   indices  = (int*)(ws + 528384);              // 256 KiB
  float* partials = (float*)(ws + 790528);            // 8 KiB

  prep_kernel<<<NCODES, 64, 0, stream>>>(ew, ebf, cneg);
  argmin_kernel<<<M_ROWS / 128, 256, 0, stream>>>(x, ebf, cneg, indices);
  gather_kernel<<<2048, 256, 0, stream>>>(x, ew, indices, out, partials);
  loss_kernel<<<1, 256, 0, stream>>>(partials, out + 16777216);
}

// Round 2
// 77.121 us; speedup vs baseline: 1.3066x; 1.3066x over previous
//
#include <hip/hip_runtime.h>
#include <hip/hip_bf16.h>

// Quantizer (VQ-VAE): inputs [32,2048,256] f32, embed [1024,256] f32.
// out = (quantized [32,2048,256] f32, latent_loss scalar f32) concatenated.
//
// Pipeline:
//   prep_kernel : embed -> bf16 PRE-SWIZZLED copy (ws) + cneg[k] = -0.5*||e_k||^2
//   vq_kernel   : X->regs (once), Es chunks via global_load_lds, bf16-MFMA argmin,
//                 fused q = ew[code] write + algebraic loss partials
//   loss_kernel : final reduce -> 1.25 * [sum(x^2) - 2*sum(sv_win)] / (N*D)
//
// loss algebra: ||x-e||^2 = ||x||^2 - 2*(x.e - 0.5||e||^2) = ||x||^2 - 2*sv.
// sv_win is recovered from the packed argmin key (low 10 mantissa bits carry
// the code index; truncation error <= ~2e-6, bf16 dot noise ~3e-5 -- both far
// below the 2.5e-2 threshold).

#define DIM     256
#define M_ROWS  65536
#define NCODES  1024

using bf16x8  = __attribute__((ext_vector_type(8))) short;
using f32x4   = __attribute__((ext_vector_type(4))) float;
using short4v = __attribute__((ext_vector_type(4))) short;

__device__ inline short f2bf(float f) {
  union { __hip_bfloat16 h; short s; } u;
  u.h = __float2bfloat16(f);   // RTNE
  return u.s;
}

__device__ inline void gload_lds16(const short* g, short* l) {
  __builtin_amdgcn_global_load_lds(
      (const __attribute__((address_space(1))) void*)g,
      (__attribute__((address_space(3))) void*)l, 16, 0, 0);
}

// ---------------------------------------------------------------- prep
// ebf layout: row-major [code][256] bf16, but 16B units within each row are
// permuted: unit u stored at position u ^ (code & 15). vq_kernel stages rows
// linearly into LDS and reads with the same XOR -> conflict-free ds_read_b128.
__global__ __launch_bounds__(64) void prep_kernel(const float* __restrict__ ew,
                                                  short* __restrict__ ebf,
                                                  float* __restrict__ cneg) {
  const int code = blockIdx.x;
  const int t    = threadIdx.x;
  float4 v = *((const float4*)(ew + (size_t)code * DIM) + t);
  short4v o;
  o.x = f2bf(v.x); o.y = f2bf(v.y); o.z = f2bf(v.z); o.w = f2bf(v.w);
  int u = t >> 1, h = t & 1;
  int off = code * 256 + ((u ^ (code & 15)) << 3) + h * 4;
  *(short4v*)(ebf + off) = o;
  float ss = v.x * v.x + v.y * v.y + v.z * v.z + v.w * v.w;
#pragma unroll
  for (int off2 = 32; off2 > 0; off2 >>= 1) ss += __shfl_xor(ss, off2, 64);
  if (t == 0) cneg[code] = -0.5f * ss;
}

// ---------------------------------------------------------------- fused vq
__global__ __launch_bounds__(256, 2) void vq_kernel(const float* __restrict__ x,
                                                    const short* __restrict__ ebf,
                                                    const float* __restrict__ cneg,
                                                    const float* __restrict__ ew,
                                                    float* __restrict__ qout,
                                                    float* __restrict__ partials) {
  __shared__ short Es[128 * 256];      // 64 KiB: X staging, then Es chunks
  __shared__ float cands[2][128];
  __shared__ int   codes[128];
  __shared__ float red[256];

  const int tid  = threadIdx.x;
  const int lane = tid & 63;
  const int wid  = tid >> 6;
  const int wr   = wid >> 1;           // wave row group (0..1), 64 rows each
  const int wc   = wid & 1;            // wave col group (0..1), 64 codes each
  const int l15  = lane & 15;
  const int lhi  = lane >> 4;          // 0..3
  const int row0 = blockIdx.x * 128;

  // ---- phase 1: stage X tile (128x256 f32 -> bf16, swizzled) + sum x^2 ----
  float x2a = 0.0f;
#pragma unroll
  for (int st = 0; st < 16; ++st) {
    int f8 = st * 256 + tid;           // 8-float unit id, 0..4095
    int r  = f8 >> 5;                  // row 0..127
    int u  = f8 & 31;                  // 16B unit within row
    const float* src = x + (size_t)(row0 + r) * DIM + u * 8;
    float4 v0 = *(const float4*)src;
    float4 v1 = *(const float4*)(src + 4);
    x2a += v0.x * v0.x + v0.y * v0.y + v0.z * v0.z + v0.w * v0.w
         + v1.x * v1.x + v1.y * v1.y + v1.z * v1.z + v1.w * v1.w;
    union { bf16x8 v; short h[8]; } pk;
    pk.h[0] = f2bf(v0.x); pk.h[1] = f2bf(v0.y); pk.h[2] = f2bf(v0.z); pk.h[3] = f2bf(v0.w);
    pk.h[4] = f2bf(v1.x); pk.h[5] = f2bf(v1.y); pk.h[6] = f2bf(v1.z); pk.h[7] = f2bf(v1.w);
    *(bf16x8*)&Es[r * 256 + ((u ^ (r & 15)) << 3)] = pk.v;
  }
  __syncthreads();

  // ---- phase 2: X fragments -> registers (live across all chunks) ----
  bf16x8 a[4][8];
#pragma unroll
  for (int mi = 0; mi < 4; ++mi)
#pragma unroll
    for (int kk = 0; kk < 8; ++kk) {
      int rr = wr * 64 + mi * 16 + l15;           // rr & 15 == l15
      int u0 = kk * 4 + lhi;
      a[mi][kk] = *(const bf16x8*)&Es[rr * 256 + ((u0 ^ l15) << 3)];
    }
  __syncthreads();

  float bk[4][4];
#pragma unroll
  for (int i = 0; i < 4; ++i)
#pragma unroll
    for (int r = 0; r < 4; ++r) bk[i][r] = -__builtin_inff();

  // ---- phase 3: 8 chunks of 128 codes ----
  for (int c = 0; c < 8; ++c) {
    const short* gbase = ebf + c * 32768;
#pragma unroll
    for (int it = 0; it < 16; ++it)
      gload_lds16(gbase + it * 2048 + tid * 8, &Es[it * 2048 + tid * 8]);
    __syncthreads();

#pragma unroll
    for (int njp = 0; njp < 2; ++njp) {
      float ct[2]; unsigned tr[2];
#pragma unroll
      for (int n2 = 0; n2 < 2; ++n2) {
        int code = c * 128 + wc * 64 + (njp * 2 + n2) * 16 + l15;
        ct[n2] = cneg[code];
        tr[n2] = (unsigned)(1023 - code);
      }
      f32x4 acc[4][2];
#pragma unroll
      for (int mi = 0; mi < 4; ++mi)
#pragma unroll
        for (int n2 = 0; n2 < 2; ++n2) acc[mi][n2] = f32x4{0.f, 0.f, 0.f, 0.f};

#pragma unroll
      for (int kk = 0; kk < 8; ++kk) {
        int u0 = kk * 4 + lhi;
        bf16x8 b[2];
#pragma unroll
        for (int n2 = 0; n2 < 2; ++n2) {
          int cl = wc * 64 + (njp * 2 + n2) * 16 + l15;   // cl & 15 == l15
          b[n2] = *(const bf16x8*)&Es[cl * 256 + ((u0 ^ l15) << 3)];
        }
#pragma unroll
        for (int mi = 0; mi < 4; ++mi)
#pragma unroll
          for (int n2 = 0; n2 < 2; ++n2)
            acc[mi][n2] = __builtin_amdgcn_mfma_f32_16x16x32_bf16(a[mi][kk], b[n2], acc[mi][n2], 0, 0, 0);
      }

      // fold into running best keys: key = (sv & ~1023) | (1023-code)
#pragma unroll
      for (int mi = 0; mi < 4; ++mi)
#pragma unroll
        for (int n2 = 0; n2 < 2; ++n2)
#pragma unroll
          for (int r = 0; r < 4; ++r) {
            float sv = acc[mi][n2][r] + ct[n2];
            unsigned kb = (__float_as_uint(sv) & 0xFFFFFC00u) | tr[n2];
            bk[mi][r] = fmaxf(bk[mi][r], __uint_as_float(kb));
          }
    }
    __syncthreads();   // protect Es before next chunk staging
  }

  // ---- phase 4: reduce across 16 code-lanes, resolve per-row winner ----
#pragma unroll
  for (int mi = 0; mi < 4; ++mi)
#pragma unroll
    for (int r = 0; r < 4; ++r) {
      float v = bk[mi][r];
#pragma unroll
      for (int off = 1; off < 16; off <<= 1) v = fmaxf(v, __shfl_xor(v, off, 64));
      if (l15 == 0) cands[wc][wr * 64 + mi * 16 + lhi * 4 + r] = v;
    }
  __syncthreads();

  float sv = 0.0f;
  if (tid < 128) {
    float k = fmaxf(cands[0][tid], cands[1][tid]);
    unsigned ku = __float_as_uint(k);
    codes[tid] = 1023 - (int)(ku & 1023u);
    sv = __uint_as_float(ku & 0xFFFFFC00u);
  }
  red[tid] = x2a - 2.0f * sv;          // block partial: sum x^2 - 2*sum sv
  __syncthreads();
  for (int s = 128; s > 0; s >>= 1) {
    if (tid < s) red[tid] += red[tid + s];
    __syncthreads();
  }
  if (tid == 0) partials[blockIdx.x] = red[0];

  // ---- phase 5: fused gather write q = ew[code] (exact fp32, coalesced) ----
#pragma unroll 8
  for (int j = 0; j < 32; ++j) {
    int f4 = j * 256 + tid;            // float4 id within the 128x256 tile
    int rw = f4 >> 6;
    int c4 = f4 & 63;
    int code = codes[rw];
    float4 qv = *((const float4*)(ew + (size_t)code * DIM) + c4);
    *((float4*)(qout + (size_t)(row0 + rw) * DIM) + c4) = qv;
  }
}

// ---------------------------------------------------------------- final loss
__global__ __launch_bounds__(256) void loss_kernel(const float* __restrict__ partials,
                                                   float* __restrict__ out_loss) {
  __shared__ double red[256];
  double a = 0.0;
  for (int i = threadIdx.x; i < 512; i += 256) a += (double)partials[i];
  red[threadIdx.x] = a;
  __syncthreads();
  for (int s = 128; s > 0; s >>= 1) {
    if (threadIdx.x < s) red[threadIdx.x] += red[threadIdx.x + s];
    __syncthreads();
  }
  if (threadIdx.x == 0) out_loss[0] = (float)(1.25 * red[0] / 16777216.0);
}

// ---------------------------------------------------------------- launch
extern "C" void kernel_launch(void* const* d_in, const int* in_sizes, int n_in,
                              void* d_out, int out_size, void* d_ws, size_t ws_size,
                              hipStream_t stream) {
  const float* x  = (const float*)d_in[0];   // inputs [65536,256]
  const float* ew = (const float*)d_in[1];   // embed  [1024,256]
  float* out = (float*)d_out;

  char* ws = (char*)d_ws;
  short* ebf      = (short*)ws;                       // 512 KiB (pre-swizzled bf16)
  float* cneg     = (float*)(ws + 524288);            // 4 KiB
  float* partials = (float*)(ws + 528384);            // 2 KiB

  prep_kernel<<<NCODES, 64, 0, stream>>>(ew, ebf, cneg);
  vq_kernel<<<M_ROWS / 128, 256, 0, stream>>>(x, ebf, cneg, ew, out, partials);
  loss_kernel<<<1, 256, 0, stream>>>(partials, out + 16777216);
}